// Round 2
// baseline (1377.611 us; speedup 1.0000x reference)
//
#include <hip/hip_runtime.h>
#include <hip/hip_bf16.h>

typedef __bf16 bf16x8 __attribute__((ext_vector_type(8)));
typedef __bf16 bf16x4 __attribute__((ext_vector_type(4)));
typedef float  f32x4  __attribute__((ext_vector_type(4)));

static constexpr int BB   = 1024;   // batch
static constexpr int INF  = 256;    // IN
static constexpr int LATF = 512;    // LAT
static constexpr int HIDF = 1024;   // HID
static constexpr int OUTF = 64;     // OUT
static constexpr float DT = 0.05f;  // (T1-T0)/N_STEPS

__device__ __forceinline__ void gload_lds16(const __bf16* g, __bf16* l) {
    __builtin_amdgcn_global_load_lds(
        (const __attribute__((address_space(1))) void*)g,
        (__attribute__((address_space(3))) void*)l, 16, 0, 0);
}

// ---------------- fused prep: x->bf16 + 3 weight transposes ----------------
// grid 1408 blocks of (32,8):
//   [0,256)     : conv x (1024x256 fp32 -> bf16), 4 elems/thread
//   [256,384)   : W_in (256x512)  -> WinT (512x256)
//   [384,896)   : W1   (512x1024) -> W1T  (1024x512)   (row 512 of W1 excluded)
//   [896,1408)  : W2   (1024x512) -> W2T  (512x1024)
__global__ __launch_bounds__(256)
void prep_k(const float* __restrict__ x, __bf16* __restrict__ xb,
            const float* __restrict__ W_in, __bf16* __restrict__ WinT,
            const float* __restrict__ W1, __bf16* __restrict__ W1T,
            const float* __restrict__ W2, __bf16* __restrict__ W2T) {
    const int b = blockIdx.x;
    const int tx = threadIdx.x, ty = threadIdx.y;
    if (b < 256) {
        const int i = b * 256 + ty * 32 + tx;
        float4 v = reinterpret_cast<const float4*>(x)[i];
        bf16x4 o;
        o[0] = (__bf16)v.x; o[1] = (__bf16)v.y; o[2] = (__bf16)v.z; o[3] = (__bf16)v.w;
        reinterpret_cast<bf16x4*>(xb)[i] = o;
        return;
    }
    const float* src; __bf16* dst; int R, C, tb;
    if (b < 384)      { src = W_in; dst = WinT; R = 256;  C = 512;  tb = b - 256; }
    else if (b < 896) { src = W1;   dst = W1T;  R = 512;  C = 1024; tb = b - 384; }
    else              { src = W2;   dst = W2T;  R = 1024; C = 512;  tb = b - 896; }
    __shared__ float tile[32][33];
    const int nbc = C / 32;
    const int c0 = (tb % nbc) * 32, r0 = (tb / nbc) * 32;
#pragma unroll
    for (int i = 0; i < 32; i += 8)
        tile[ty + i][tx] = src[(size_t)(r0 + ty + i) * C + (c0 + tx)];
    __syncthreads();
#pragma unroll
    for (int i = 0; i < 32; i += 8)
        dst[(size_t)(c0 + ty + i) * R + (r0 + tx)] = (__bf16)tile[tx][ty + i];
}

// ---------------- fused GEMM: C = A(bf16, MxK) @ Bt(bf16, NxK)^T ----------------
// BM x 32 tile, BK=64, 256 threads = 4 waves. BM=64: waves 2x2 (wave 32x16);
// BM=32: waves 2x2 (wave 16x16). Double-buffered LDS via global_load_lds
// (linear dest, pre-swizzled global source, XOR-swizzled ds_read — rule #21).
// MODE 0: h0    : v = tanh(acc + bias[col]);           h=v, zb=bf16(v)        (N=LAT)
// MODE 1: dynG1 : v = tanh(acc + bias[col]+t*wl[col]); gb=bf16(v)             (N=HID)
// MODE 2: dynG2 : kv = acc + bias[col]; kout=kv; zb=bf16(h + coef*kv)         (N=LAT)
// MODE 3: dynG2k4: kv=acc+bias; h += DT/6*(k1+2k2+2k3+kv); zb=bf16(h)         (N=LAT)
template <int BM, int MODE>
__global__ __launch_bounds__(256, 2)
void gemm_k(const __bf16* __restrict__ A, const __bf16* __restrict__ Bt, const int K,
            float* __restrict__ hbuf, __bf16* __restrict__ zb, __bf16* __restrict__ gb,
            float* __restrict__ kout, const float* __restrict__ kb1,
            const float* __restrict__ kb2, const float* __restrict__ kb3,
            const float* __restrict__ bias, const float* __restrict__ wlast,
            const float tval, const float coef) {
    constexpr int MI = BM / 32;  // M-fragments per wave (2 or 1)
    constexpr int BN = 32, BK = 64;
    __shared__ __align__(16) __bf16 As[2][BM][BK];
    __shared__ __align__(16) __bf16 Bs[2][BN][BK];

    const int tid  = threadIdx.x;
    const int lane = tid & 63;
    const int wv   = tid >> 6;
    const int wr   = wv >> 1, wc = wv & 1;
    const int m0   = blockIdx.x * BM;
    const int n0   = blockIdx.y * BN;
    const int KT   = K >> 6;

    // staging: 1KB chunks (8 rows x 128B). lane l -> row lr8=l>>3, phys granule l&7.
    // source fetches logical granule (l&7)^lr8 so a linear LDS write realizes the swizzle.
    const int lr8 = lane >> 3;
    const int lq  = ((lane & 7) ^ lr8) << 3;  // bf16 offset within BK row
    const __bf16* aSrc = A  + (size_t)(m0 + 8 * MI * wv + lr8) * K + lq;
    const __bf16* bSrc = Bt + (size_t)(n0 + 8 * wv + lr8) * K + lq;

    auto STAGE = [&](int buf, int kt) {
        const __bf16* ap = aSrc + (size_t)kt * BK;
#pragma unroll
        for (int c = 0; c < MI; ++c)
            gload_lds16(ap + (size_t)(8 * c) * K, &As[buf][8 * MI * wv + 8 * c][0]);
        gload_lds16(bSrc + (size_t)kt * BK, &Bs[buf][8 * wv][0]);
    };

    STAGE(0, 0);

    f32x4 acc[MI];
#pragma unroll
    for (int mi = 0; mi < MI; ++mi) acc[mi] = f32x4{0.f, 0.f, 0.f, 0.f};

    const int fr = lane & 15;   // row-in-frag (A) / col-in-frag (B)
    const int kq = lane >> 4;   // k-granule index 0..3

    __syncthreads();

    for (int kt = 0; kt < KT; ++kt) {
        const int cur = kt & 1;
        if (kt + 1 < KT) STAGE(cur ^ 1, kt + 1);

        bf16x8 af[MI][2], bfr[2];
#pragma unroll
        for (int mi = 0; mi < MI; ++mi) {
            const int row = wr * (16 * MI) + mi * 16 + fr;
            const int s = row & 7;
#pragma unroll
            for (int ks = 0; ks < 2; ++ks)
                af[mi][ks] = *reinterpret_cast<const bf16x8*>(
                    &As[cur][row][((ks * 4 + kq) ^ s) << 3]);
        }
        {
            const int col = wc * 16 + fr;
            const int s = col & 7;
#pragma unroll
            for (int ks = 0; ks < 2; ++ks)
                bfr[ks] = *reinterpret_cast<const bf16x8*>(
                    &Bs[cur][col][((ks * 4 + kq) ^ s) << 3]);
        }
#pragma unroll
        for (int mi = 0; mi < MI; ++mi) {
            acc[mi] = __builtin_amdgcn_mfma_f32_16x16x32_bf16(af[mi][0], bfr[0], acc[mi], 0, 0, 0);
            acc[mi] = __builtin_amdgcn_mfma_f32_16x16x32_bf16(af[mi][1], bfr[1], acc[mi], 0, 0, 0);
        }
        __syncthreads();
    }

    // epilogue. D mapping (m89-verified): col = lane&15, row = (lane>>4)*4 + j
    const int lr = kq << 2;
    const int lc = fr;
#pragma unroll
    for (int mi = 0; mi < MI; ++mi) {
#pragma unroll
        for (int j = 0; j < 4; ++j) {
            const int row = m0 + wr * (16 * MI) + mi * 16 + lr + j;
            const int col = n0 + wc * 16 + lc;
            const float a = acc[mi][j];
            if (MODE == 0) {
                const float v = tanhf(a + bias[col]);
                const int idx = row * LATF + col;
                hbuf[idx] = v;
                zb[idx]   = (__bf16)v;
            } else if (MODE == 1) {
                const float v = tanhf(a + bias[col] + tval * wlast[col]);
                gb[row * HIDF + col] = (__bf16)v;
            } else if (MODE == 2) {
                const int idx = row * LATF + col;
                const float kv = a + bias[col];
                kout[idx] = kv;
                zb[idx]   = (__bf16)(hbuf[idx] + coef * kv);
            } else {
                const int idx = row * LATF + col;
                const float kv = a + bias[col];
                const float hn = hbuf[idx] + (DT / 6.0f) *
                                 (kb1[idx] + 2.0f * kb2[idx] + 2.0f * kb3[idx] + kv);
                hbuf[idx] = hn;
                zb[idx]   = (__bf16)hn;
            }
        }
    }
}

// ---------------- out = h[:, :256] @ W_out + b_out (fp32) ----------------
__global__ __launch_bounds__(256)
void out_k(const float* __restrict__ h, const float* __restrict__ Wout,
           const float* __restrict__ bout, float* __restrict__ out) {
    const int col = threadIdx.x & 63;
    const int rg  = threadIdx.x >> 6;
    const int r0  = blockIdx.x * 16 + rg * 4;
    float a0 = 0.f, a1 = 0.f, a2 = 0.f, a3 = 0.f;
    for (int k = 0; k < INF; ++k) {
        const float w = Wout[k * OUTF + col];
        a0 += h[(r0 + 0) * LATF + k] * w;
        a1 += h[(r0 + 1) * LATF + k] * w;
        a2 += h[(r0 + 2) * LATF + k] * w;
        a3 += h[(r0 + 3) * LATF + k] * w;
    }
    const float b = bout[col];
    out[(r0 + 0) * OUTF + col] = a0 + b;
    out[(r0 + 1) * OUTF + col] = a1 + b;
    out[(r0 + 2) * OUTF + col] = a2 + b;
    out[(r0 + 3) * OUTF + col] = a3 + b;
}

extern "C" void kernel_launch(void* const* d_in, const int* in_sizes, int n_in,
                              void* d_out, int out_size, void* d_ws, size_t ws_size,
                              hipStream_t stream) {
    const float* x     = (const float*)d_in[0];
    const float* W_in  = (const float*)d_in[1];
    const float* b_in  = (const float*)d_in[2];
    const float* W1    = (const float*)d_in[3];   // (LAT+1, HID)
    const float* b1    = (const float*)d_in[4];
    const float* W2    = (const float*)d_in[5];   // (HID, LAT)
    const float* b2    = (const float*)d_in[6];
    const float* W_out = (const float*)d_in[7];   // (LAT/2, OUT)
    const float* b_out = (const float*)d_in[8];
    float* out = (float*)d_out;

    char* ws = (char*)d_ws;
    size_t off = 0;
    auto alloc = [&](size_t bytes) {
        void* p = ws + off;
        off += (bytes + 255) & ~(size_t)255;
        return p;
    };
    __bf16* xb   = (__bf16*)alloc((size_t)BB * INF * 2);
    __bf16* WinT = (__bf16*)alloc((size_t)LATF * INF * 2);   // [LAT][IN]
    __bf16* W1T  = (__bf16*)alloc((size_t)HIDF * LATF * 2);  // [HID][LAT]
    __bf16* W2T  = (__bf16*)alloc((size_t)LATF * HIDF * 2);  // [LAT][HID]
    float*  h    = (float*)alloc((size_t)BB * LATF * 4);
    __bf16* zbuf = (__bf16*)alloc((size_t)BB * LATF * 2);
    __bf16* gbuf = (__bf16*)alloc((size_t)BB * HIDF * 2);
    float*  k1   = (float*)alloc((size_t)BB * LATF * 4);
    float*  k2   = (float*)alloc((size_t)BB * LATF * 4);
    float*  k3   = (float*)alloc((size_t)BB * LATF * 4);
    if (off > ws_size) return;

    prep_k<<<1408, dim3(32, 8), 0, stream>>>(x, xb, W_in, WinT, W1, W1T, W2, W2T);

    const float* w1last = W1 + (size_t)LATF * HIDF;  // row 512 of W1 (t coefficients)

    // h0 = tanh(x @ W_in + b_in): M=1024, N=512, K=256
    gemm_k<64, 0><<<dim3(BB / 64, LATF / 32), 256, 0, stream>>>(
        xb, WinT, INF, h, zbuf, nullptr, nullptr, nullptr, nullptr, nullptr,
        b_in, nullptr, 0.f, 0.f);

    for (int s = 0; s < 20; ++s) {
        const float t0 = DT * (float)s;
        const float th = t0 + 0.5f * DT;
        const float t1 = t0 + DT;
        // k1
        gemm_k<64, 1><<<dim3(BB / 64, HIDF / 32), 256, 0, stream>>>(
            zbuf, W1T, LATF, nullptr, nullptr, gbuf, nullptr, nullptr, nullptr, nullptr,
            b1, w1last, t0, 0.f);
        gemm_k<32, 2><<<dim3(BB / 32, LATF / 32), 256, 0, stream>>>(
            gbuf, W2T, HIDF, h, zbuf, nullptr, k1, nullptr, nullptr, nullptr,
            b2, nullptr, 0.f, 0.5f * DT);
        // k2
        gemm_k<64, 1><<<dim3(BB / 64, HIDF / 32), 256, 0, stream>>>(
            zbuf, W1T, LATF, nullptr, nullptr, gbuf, nullptr, nullptr, nullptr, nullptr,
            b1, w1last, th, 0.f);
        gemm_k<32, 2><<<dim3(BB / 32, LATF / 32), 256, 0, stream>>>(
            gbuf, W2T, HIDF, h, zbuf, nullptr, k2, nullptr, nullptr, nullptr,
            b2, nullptr, 0.f, 0.5f * DT);
        // k3
        gemm_k<64, 1><<<dim3(BB / 64, HIDF / 32), 256, 0, stream>>>(
            zbuf, W1T, LATF, nullptr, nullptr, gbuf, nullptr, nullptr, nullptr, nullptr,
            b1, w1last, th, 0.f);
        gemm_k<32, 2><<<dim3(BB / 32, LATF / 32), 256, 0, stream>>>(
            gbuf, W2T, HIDF, h, zbuf, nullptr, k3, nullptr, nullptr, nullptr,
            b2, nullptr, 0.f, DT);
        // k4 + state update
        gemm_k<64, 1><<<dim3(BB / 64, HIDF / 32), 256, 0, stream>>>(
            zbuf, W1T, LATF, nullptr, nullptr, gbuf, nullptr, nullptr, nullptr, nullptr,
            b1, w1last, t1, 0.f);
        gemm_k<32, 3><<<dim3(BB / 32, LATF / 32), 256, 0, stream>>>(
            gbuf, W2T, HIDF, h, zbuf, nullptr, nullptr, k1, k2, k3,
            b2, nullptr, 0.f, 0.f);
    }

    out_k<<<BB / 16, 256, 0, stream>>>(h, W_out, b_out, out);
}